// Round 8
// baseline (729.545 us; speedup 1.0000x reference)
//
#include <hip/hip_runtime.h>
#include <hip/hip_bf16.h>
#include <cstdint>

typedef __attribute__((ext_vector_type(8))) short bf16x8;
typedef __attribute__((ext_vector_type(4))) float f32x4;

#define MFMA16(a, b, c) __builtin_amdgcn_mfma_f32_16x16x32_bf16((a), (b), (c), 0, 0, 0)

__device__ __forceinline__ ushort f2bf(float x) {
  union { float f; uint32_t u; } c; c.f = x;
  uint32_t r = (c.u + 0x7FFFu + ((c.u >> 16) & 1u)) >> 16;
  return (ushort)r;
}

__device__ __forceinline__ void gload_lds16(const ushort* g, ushort* l) {
  __builtin_amdgcn_global_load_lds((__attribute__((address_space(1))) void*)g,
                                   (__attribute__((address_space(3))) void*)l, 16, 0, 0);
}

// ---- BK=64 staging (128B rows), swizzle ((r&7)<<4): free 2-way on read ----
template <int NW, int INSTR>
__device__ __forceinline__ void stageT(const ushort* __restrict__ tileBase, int ld,
                                       ushort* lds, int wid, int lane) {
#pragma unroll
  for (int q = 0; q < INSTR; q++) {
    int r = (wid * INSTR + q) * 8 + (lane >> 3);
    int cb = ((lane & 7) * 16) ^ ((r & 7) << 4);
    gload_lds16(tileBase + (long)r * ld + (cb >> 1), lds + (wid * INSTR + q) * 512);
  }
}

__device__ __forceinline__ bf16x8 frag_read(const ushort* lds, int r, int kb) {
  int off = r * 128 + (kb ^ ((r & 7) << 4));
  return *(const bf16x8*)((const char*)lds + off);
}

// ---- inline top-2 over 16 expert probs ----
__device__ __forceinline__ void top2(const float* __restrict__ p, int& i0, int& i1,
                                     float& p0, float& p1) {
  float v0 = -1e30f, v1 = -1e30f; i0 = 0; i1 = 0;
#pragma unroll
  for (int e = 0; e < 16; e++) {
    float v = p[e];
    if (v > v0) { v1 = v0; i1 = i0; v0 = v; i0 = e; }
    else if (v > v1) { v1 = v; i1 = e; }
  }
  float s = 1.0f / (v0 + v1 + 1e-8f);
  p0 = v0 * s; p1 = v1 * s;
}

// -------- f32 -> bf16: hidden + Wout + selected experts (sel inline) --------
__global__ void cvt_all(const float* __restrict__ hidden, const float* __restrict__ wout,
                        const float* __restrict__ eprobs,
                        const float* __restrict__ Wg, const float* __restrict__ Wu,
                        const float* __restrict__ Wd,
                        ushort* __restrict__ h_bf, ushort* __restrict__ wo_bf,
                        ushort* __restrict__ wg_bf, ushort* __restrict__ wu_bf,
                        ushort* __restrict__ wd_bf) {
  __shared__ unsigned smask;
  if (threadIdx.x == 0) {
    unsigned m = 0;
    for (int b = 0; b < 8; b++) {
      int i0, i1; float q0, q1;
      top2(eprobs + b * 16, i0, i1, q0, q1);
      m |= (1u << i0) | (1u << i1);
    }
    smask = m;
  }
  __syncthreads();
  const unsigned selm = smask;

  const long h4 = 2097152L / 4, w4 = 16384000L / 4;
  const long e4 = 1048576L / 4;            // float4s per expert matrix
  const long n4 = h4 + w4 + 48 * e4;
  long stride = (long)gridDim.x * blockDim.x;
  for (long g = (long)blockIdx.x * blockDim.x + threadIdx.x; g < n4; g += stride) {
    const float* src; ushort* dst; long o;
    if (g < h4) { src = hidden; dst = h_bf; o = g; }
    else if (g < h4 + w4) { src = wout; dst = wo_bf; o = g - h4; }
    else {
      long idx = g - h4 - w4;
      int m = (int)(idx / (16 * e4));
      long rem = idx - (long)m * 16 * e4;
      int e = (int)(rem / e4);
      if (!((selm >> e) & 1u)) continue;
      src = (m == 0 ? Wg : (m == 1 ? Wu : Wd));
      dst = (m == 0 ? wg_bf : (m == 1 ? wu_bf : wd_bf));
      o = rem;
    }
    float4 v = ((const float4*)src)[o];
    ((ushort4*)dst)[o] = make_ushort4(f2bf(v.x), f2bf(v.y), f2bf(v.z), f2bf(v.w));
  }
}

// -------- fused gate/up, BM=256 x BN=128, dual-B, 8 waves, counted vmcnt --------
__global__ __launch_bounds__(512, 2) void gateup256(
    const ushort* __restrict__ Hb, const ushort* __restrict__ Wg,
    const ushort* __restrict__ Wu, const float* __restrict__ eprobs,
    ushort* __restrict__ G) {
  constexpr int Hd = 512, I = 2048, S = 512, NT = Hd / 64;
  __shared__ ushort As[2][256 * 64], B1s[2][128 * 64], B2s[2][128 * 64];  // 128 KiB

  int wg = blockIdx.x;
  int swz = (wg & 7) * 64 + (wg >> 3);
  int p = swz >> 5;
  int r5 = swz & 31;
  int rowT = r5 & 1, colT = r5 >> 1;
  const int b = p >> 1;
  int i0, i1; float q0, q1;
  top2(eprobs + b * 16, i0, i1, q0, q1);
  const int eid = (p & 1) ? i1 : i0;
  const int row0 = rowT * 256, col0 = colT * 128;
  const ushort* Ab  = Hb + (long)b * S * Hd + (long)row0 * Hd;
  const ushort* B1b = Wg + (long)eid * I * Hd + (long)col0 * Hd;
  const ushort* B2b = Wu + (long)eid * I * Hd + (long)col0 * Hd;

  const int tid = threadIdx.x, wid = tid >> 6, lane = tid & 63;
  const int wr = wid >> 2, wc = wid & 3;   // wave tile: 128 rows x 32 cols

  f32x4 acc1[8][2] = {};
  f32x4 acc2[8][2] = {};

  auto stage_gu = [&](int kt, int buf) {
    stageT<8, 4>(Ab + kt * 64, Hd, As[buf], wid, lane);
    stageT<8, 2>(B1b + kt * 64, Hd, B1s[buf], wid, lane);
    stageT<8, 2>(B2b + kt * 64, Hd, B2s[buf], wid, lane);
  };

  stage_gu(0, 0);  // 8 vm ops

  for (int kt = 0; kt < NT; kt++) {
    if (kt + 1 < NT) stage_gu(kt + 1, (kt + 1) & 1);  // 8 vm ops
    if (kt + 1 < NT) asm volatile("s_waitcnt vmcnt(8)" ::: "memory");
    else             asm volatile("s_waitcnt vmcnt(0)" ::: "memory");
    __builtin_amdgcn_s_barrier();
    __builtin_amdgcn_sched_barrier(0);
    const ushort* as = As[kt & 1];
    const ushort* b1 = B1s[kt & 1];
    const ushort* b2 = B2s[kt & 1];
#pragma unroll
    for (int ks = 0; ks < 2; ks++) {
      const int kb = ks * 64 + ((lane >> 4) * 16);
      bf16x8 av[8], b1v[2], b2v[2];
#pragma unroll
      for (int i = 0; i < 8; i++) av[i] = frag_read(as, wr * 128 + i * 16 + (lane & 15), kb);
#pragma unroll
      for (int j = 0; j < 2; j++) b1v[j] = frag_read(b1, wc * 32 + j * 16 + (lane & 15), kb);
      __builtin_amdgcn_s_setprio(1);
#pragma unroll
      for (int i = 0; i < 8; i++)
#pragma unroll
        for (int j = 0; j < 2; j++) acc1[i][j] = MFMA16(av[i], b1v[j], acc1[i][j]);
      __builtin_amdgcn_s_setprio(0);
#pragma unroll
      for (int j = 0; j < 2; j++) b2v[j] = frag_read(b2, wc * 32 + j * 16 + (lane & 15), kb);
      __builtin_amdgcn_s_setprio(1);
#pragma unroll
      for (int i = 0; i < 8; i++)
#pragma unroll
        for (int j = 0; j < 2; j++) acc2[i][j] = MFMA16(av[i], b2v[j], acc2[i][j]);
      __builtin_amdgcn_s_setprio(0);
    }
    asm volatile("s_waitcnt lgkmcnt(0)" ::: "memory");
    __builtin_amdgcn_sched_barrier(0);
    __builtin_amdgcn_s_barrier();
  }

  ushort* Gout = G + (long)p * S * I;
#pragma unroll
  for (int i = 0; i < 8; i++) {
    int r = row0 + wr * 128 + i * 16 + ((lane >> 4) * 4);
#pragma unroll
    for (int j = 0; j < 2; j++) {
      int c = col0 + wc * 32 + j * 16 + (lane & 15);
#pragma unroll
      for (int q = 0; q < 4; q++) {
        float g = acc1[i][j][q], u = acc2[i][j][q];
        float sg = g / (1.0f + __expf(-g));
        Gout[(long)(r + q) * I + c] = f2bf(sg * u);
      }
    }
  }
}

// ---------------- fused down GEMM + weighted combine -> bf16 Cb ----------------
__global__ __launch_bounds__(256) void down_fused(
    const ushort* __restrict__ G, const ushort* __restrict__ Wd,
    const float* __restrict__ eprobs, ushort* __restrict__ Cb) {
  constexpr int I = 2048, Hd = 512, S = 512, NT = 64;
  const int b = blockIdx.z;
  const int row0 = blockIdx.x * 128, col0 = blockIdx.y * 64;
  __shared__ ushort As[2][128 * 64], Bs[2][64 * 64];  // 48 KiB
  const int tid = threadIdx.x, wid = tid >> 6, lane = tid & 63;
  const int wr = wid >> 1, wc = wid & 1;   // wave 64 x 32
  int e0, e1; float p0, p1;
  top2(eprobs + b * 16, e0, e1, p0, p1);
  const ushort* A0 = G + ((long)(2 * b) * S + row0) * I;
  const ushort* A1 = G + ((long)(2 * b + 1) * S + row0) * I;
  const ushort* B0 = Wd + ((long)e0 * Hd + col0) * I;
  const ushort* B1 = Wd + ((long)e1 * Hd + col0) * I;

  f32x4 acc[4][2] = {};

  auto stageD = [&](int t2, int buf) {
    const ushort* An = (t2 < 32 ? A0 + t2 * 64 : A1 + (t2 - 32) * 64);
    const ushort* Bn = (t2 < 32 ? B0 + t2 * 64 : B1 + (t2 - 32) * 64);
    stageT<4, 4>(An, I, As[buf], wid, lane);
    stageT<4, 2>(Bn, I, Bs[buf], wid, lane);
  };

  stageD(0, 0);  // 6 vm ops

  for (int t = 0; t < NT; t++) {
    if (t + 1 < NT) stageD(t + 1, (t + 1) & 1);  // 6 vm ops
    if (t + 1 < NT) asm volatile("s_waitcnt vmcnt(6)" ::: "memory");
    else            asm volatile("s_waitcnt vmcnt(0)" ::: "memory");
    __builtin_amdgcn_s_barrier();
    __builtin_amdgcn_sched_barrier(0);
    if (t == 32) {
      float ratio = p0 / p1;
#pragma unroll
      for (int i = 0; i < 4; i++)
#pragma unroll
        for (int j = 0; j < 2; j++) acc[i][j] *= ratio;
    }
#pragma unroll
    for (int ks = 0; ks < 2; ks++) {
      const int kb = ks * 64 + ((lane >> 4) * 16);
      bf16x8 av[4], bv[2];
#pragma unroll
      for (int i = 0; i < 4; i++) av[i] = frag_read(As[t & 1], wr * 64 + i * 16 + (lane & 15), kb);
#pragma unroll
      for (int j = 0; j < 2; j++) bv[j] = frag_read(Bs[t & 1], wc * 32 + j * 16 + (lane & 15), kb);
      __builtin_amdgcn_s_setprio(1);
#pragma unroll
      for (int i = 0; i < 4; i++)
#pragma unroll
        for (int j = 0; j < 2; j++) acc[i][j] = MFMA16(av[i], bv[j], acc[i][j]);
      __builtin_amdgcn_s_setprio(0);
    }
    asm volatile("s_waitcnt lgkmcnt(0)" ::: "memory");
    __builtin_amdgcn_sched_barrier(0);
    __builtin_amdgcn_s_barrier();
  }

  ushort* Co = Cb + ((long)b * S + row0) * Hd + col0;
#pragma unroll
  for (int i = 0; i < 4; i++) {
    int r = wr * 64 + i * 16 + ((lane >> 4) * 4);
#pragma unroll
    for (int j = 0; j < 2; j++) {
      int c = wc * 32 + j * 16 + (lane & 15);
#pragma unroll
      for (int q = 0; q < 4; q++)
        Co[(long)(r + q) * Hd + c] = f2bf(p1 * acc[i][j][q]);
    }
  }
}

// -------- final projection: 256x256, 8 waves, 4-phase pipelined, LDS-coalesced epilogue --------
__global__ __launch_bounds__(512, 2) void gemm256_final(
    const ushort* __restrict__ A,   // [4096][512] bf16 (combined)
    const ushort* __restrict__ B,   // [32000][512] bf16 (Wout)
    float* __restrict__ Out) {      // [4096][32000] f32
  constexpr int K = 512, NT = K / 64, LDC = 32000;
  __shared__ ushort shm[65536];     // 128 KiB: As = shm[0..32767], Bs = shm[32768..]

  int wg = blockIdx.x;                         // 2000 blocks
  int swz = (wg & 7) * 250 + (wg >> 3);
  const int colT = swz / 16, rowT = swz % 16;  // 16 row-tiles share each B col-tile
  const int row0 = rowT * 256, col0 = colT * 256;

  const int tid = threadIdx.x, wid = tid >> 6, lane = tid & 63;
  const int wr = wid >> 2, wc = wid & 3;       // wave tile: 128 rows x 64 cols
  const int l15 = lane & 15;

  const ushort* Ab = A + (long)row0 * K;
  const ushort* Bb = B + (long)col0 * K;
  f32x4 acc[8][4] = {};

  auto aPtr = [&](int t2, int h) { return shm + ((t2 & 1) * 2 + h) * 8192; };
  auto bPtr = [&](int t2, int h) { return shm + 32768 + ((t2 & 1) * 2 + h) * 8192; };
  auto stA = [&](int t2, int h) {
    stageT<8, 2>(Ab + (long)(h * 128) * K + t2 * 64, K, aPtr(t2, h), wid, lane);
  };
  auto stB = [&](int t2, int h) {
    stageT<8, 2>(Bb + (long)(h * 128) * K + t2 * 64, K, bPtr(t2, h), wid, lane);
  };

  // prologue: tile 0 complete (4 half-stages), then B halves of tile 1
  stA(0, 0); stA(0, 1); stB(0, 0); stB(0, 1);
  stB(1, 0); stB(1, 1);

  for (int t = 0; t < NT; t++) {
    const ushort* aH = aPtr(t, wr);            // this wave's A-half
    const ushort* bH = bPtr(t, wc >> 1);       // this wave's B-half
    const int bRow = (wc & 1) * 64;

    bf16x8 av[4][2], bv0[2][2], bv1[2][2];

    // ---- P1: Q(M0,N0) ----
    if (t < NT - 1) asm volatile("s_waitcnt vmcnt(4)" ::: "memory");
    else            asm volatile("s_waitcnt vmcnt(0)" ::: "memory");
    __builtin_amdgcn_s_barrier();
#pragma unroll
    for (int ks = 0; ks < 2; ks++) {
      const int kb = ks * 64 + ((lane >> 4) * 16);
#pragma unroll
      for (int i = 0; i < 4; i++) av[i][ks] = frag_read(aH, i * 16 + l15, kb);
#pragma unroll
      for (int j = 0; j < 2; j++) bv0[j][ks] = frag_read(bH, bRow + j * 16 + l15, kb);
    }
    if (t + 1 < NT) stA(t + 1, 0);
    __builtin_amdgcn_s_setprio(1);
#pragma unroll
    for (int ks = 0; ks < 2; ks++)
#pragma unroll
      for (int i = 0; i < 4; i++)
#pragma unroll
        for (int j = 0; j < 2; j++) acc[i][j] = MFMA16(av[i][ks], bv0[j][ks], acc[i][j]);
    __builtin_amdgcn_s_setprio(0);
    asm volatile("s_waitcnt lgkmcnt(0)" ::: "memory");
    __builtin_amdgcn_sched_barrier(0);
    __builtin_amdgcn_s_barrier();

    // ---- P2: Q(M0,N1) ----
#pragma unroll
    for (int ks = 0; ks < 2; ks++) {
      const int kb = ks * 64 + ((lane >> 4) * 16);
#pragma unroll
      for (int j = 0; j < 2; j++) bv1[j][ks] = frag_read(bH, bRow + 32 + j * 16 + l15, kb);
    }
    if (t + 1 < NT) stA(t + 1, 1);
    __builtin_amdgcn_s_setprio(1);
#pragma unroll
    for (int ks = 0; ks < 2; ks++)
#pragma unroll
      for (int i = 0; i < 4; i++)
#pragma unroll
        for (int j = 0; j < 2; j++) acc[i][2 + j] = MFMA16(av[i][ks], bv1[j][ks], acc[i][2 + j]);
    __builtin_amdgcn_s_setprio(0);
    asm volatile("s_waitcnt lgkmcnt(0)" ::: "memory");
    __builtin_amdgcn_sched_barrier(0);
    __builtin_amdgcn_s_barrier();

    // ---- P3: Q(M1,N0) ----
#pragma unroll
    for (int ks = 0; ks < 2; ks++) {
      const int kb = ks * 64 + ((lane >> 4) * 16);
#pragma unroll
      for (int i = 0; i < 4; i++) av[i][ks] = frag_read(aH, 64 + i * 16 + l15, kb);
    }
    if (t + 2 < NT) stB(t + 2, 0);
    __builtin_amdgcn_s_setprio(1);
#pragma unroll
    for (int ks = 0; ks < 2; ks++)
#pragma unroll
      for (int i = 0; i < 4; i++)
#pragma unroll
        for (int j = 0; j < 2; j++) acc[4 + i][j] = MFMA16(av[i][ks], bv0[j][ks], acc[4 + i][j]);
    __builtin_amdgcn_s_setprio(0);
    asm volatile("s_waitcnt lgkmcnt(0)" ::: "memory");
    __builtin_amdgcn_sched_barrier(0);
    __builtin_amdgcn_s_barrier();

    // ---- P4: Q(M1,N1)  (no ds_reads; next P1's wait+barrier separates) ----
    if (t + 2 < NT) stB(t + 2, 1);
    __builtin_amdgcn_s_setprio(1);
#pragma unroll
    for (int ks = 0; ks < 2; ks++)
#pragma unroll
      for (int i = 0; i < 4; i++)
#pragma unroll
        for (int j = 0; j < 2; j++) acc[4 + i][2 + j] = MFMA16(av[i][ks], bv1[j][ks], acc[4 + i][2 + j]);
    __builtin_amdgcn_s_setprio(0);
    __builtin_amdgcn_sched_barrier(0);
  }

  // -------- epilogue: coalesced f32 stores via LDS bounce --------
  // acc[ai][nj][q]: row_local = wr*128 + (ai>>2)*64 + (ai&3)*16 + (lane>>4)*4 + q
  //                 col_local = wc*64 + (nj>>1)*32 + (nj&1)*16 + l15
  // 8 chunks of 32 rows; stage[32][260] f32 (33.3 KB, reuses shm).
  float* stage = (float*)shm;
  constexpr int SSTR = 260;
#pragma unroll 1
  for (int ch = 0; ch < 8; ch++) {
    if (ch) __builtin_amdgcn_s_barrier();        // prev chunk readback done
    if (wr == (ch >> 2)) {
      const int aiBase = ((ch >> 1) & 1) * 4 + (ch & 1) * 2;
#pragma unroll
      for (int a1 = 0; a1 < 2; a1++) {
        const int ai = aiBase + a1;
        const int rl = a1 * 16 + ((lane >> 4) * 4);
#pragma unroll
        for (int nj = 0; nj < 4; nj++) {
          const int cl = wc * 64 + (nj >> 1) * 32 + (nj & 1) * 16 + l15;
#pragma unroll
          for (int q = 0; q < 4; q++)
            stage[(rl + q) * SSTR + cl] = acc[ai][nj][q];
        }
      }
    }
    __builtin_amdgcn_s_barrier();                // stage ready
#pragma unroll
    for (int p = 0; p < 4; p++) {
      const int rl = p * 8 + (tid >> 6);
      const int c4 = (tid & 63) * 4;
      f32x4 v = *(const f32x4*)&stage[rl * SSTR + c4];
      *(f32x4*)&Out[(long)(row0 + ch * 32 + rl) * LDC + col0 + c4] = v;
    }
  }
}

extern "C" void kernel_launch(void* const* d_in, const int* in_sizes, int n_in,
                              void* d_out, int out_size, void* d_ws, size_t ws_size,
                              hipStream_t stream) {
  const float* hidden = (const float*)d_in[0];   // [8,512,512]
  const float* eprobs = (const float*)d_in[1];   // [8,16]
  const float* Wg     = (const float*)d_in[2];   // [16,2048,512]
  const float* Wu     = (const float*)d_in[3];   // [16,2048,512]
  const float* Wd     = (const float*)d_in[4];   // [16,512,2048]
  const float* Wout   = (const float*)d_in[5];   // [32000,512]
  float* out = (float*)d_out;                    // [8,512,32000] f32

  char* ws = (char*)d_ws;
  ushort* h_bf  = (ushort*)(ws + 256);         // 8*512*512
  ushort* wg_bf = h_bf  + 2097152L;            // 16*2048*512
  ushort* wu_bf = wg_bf + 16777216L;
  ushort* wd_bf = wu_bf + 16777216L;
  ushort* wo_bf = wd_bf + 16777216L;           // 32000*512
  ushort* Gbuf  = wo_bf + 16384000L;           // 16*512*2048 bf16
  ushort* Cb    = Gbuf  + 16777216L;           // 8*512*512 bf16

  hipLaunchKernelGGL(cvt_all, dim3(4096), dim3(256), 0, stream,
                     hidden, Wout, eprobs, Wg, Wu, Wd, h_bf, wo_bf, wg_bf, wu_bf, wd_bf);
  hipLaunchKernelGGL(gateup256, dim3(512), dim3(512), 0, stream,
                     h_bf, wg_bf, wu_bf, eprobs, Gbuf);
  hipLaunchKernelGGL(down_fused, dim3(4, 8, 8), dim3(256), 0, stream,
                     Gbuf, wd_bf, eprobs, Cb);
  // output projection: 256x256 tiles, 2000 blocks x 512 thr, LDS-coalesced epilogue
  hipLaunchKernelGGL(gemm256_final, dim3(2000), dim3(512), 0, stream, Cb, wo_bf, out);
}

// Round 9
// 454.231 us; speedup vs baseline: 1.6061x; 1.6061x over previous
//
#include <hip/hip_runtime.h>
#include <hip/hip_bf16.h>
#include <cstdint>

typedef __attribute__((ext_vector_type(8))) short bf16x8;
typedef __attribute__((ext_vector_type(4))) float f32x4;

#define MFMA16(a, b, c) __builtin_amdgcn_mfma_f32_16x16x32_bf16((a), (b), (c), 0, 0, 0)

__device__ __forceinline__ ushort f2bf(float x) {
  union { float f; uint32_t u; } c; c.f = x;
  uint32_t r = (c.u + 0x7FFFu + ((c.u >> 16) & 1u)) >> 16;
  return (ushort)r;
}

__device__ __forceinline__ void gload_lds16(const ushort* g, ushort* l) {
  __builtin_amdgcn_global_load_lds((__attribute__((address_space(1))) void*)g,
                                   (__attribute__((address_space(3))) void*)l, 16, 0, 0);
}

// ---- BK=64 staging (128B rows), swizzle ((r&7)<<4): free 2-way on read ----
template <int NW, int INSTR>
__device__ __forceinline__ void stageT(const ushort* __restrict__ tileBase, int ld,
                                       ushort* lds, int wid, int lane) {
#pragma unroll
  for (int q = 0; q < INSTR; q++) {
    int r = (wid * INSTR + q) * 8 + (lane >> 3);
    int cb = ((lane & 7) * 16) ^ ((r & 7) << 4);
    gload_lds16(tileBase + (long)r * ld + (cb >> 1), lds + (wid * INSTR + q) * 512);
  }
}

__device__ __forceinline__ bf16x8 frag_read(const ushort* lds, int r, int kb) {
  int off = r * 128 + (kb ^ ((r & 7) << 4));
  return *(const bf16x8*)((const char*)lds + off);
}

// ---- BK=32 staging (64B rows). Swizzle: 16B-slot ^= (r>>1)&3.
// Bank for frag read: addr bits {r0, slot^r[2:1]} -> 8 banks x 2 lanes = free 2-way.
// gload_lds dest is linear; the SOURCE slot is pre-swizzled (rule #21).
__device__ __forceinline__ void stage32(const ushort* __restrict__ tileBase, int ld,
                                        ushort* lds, int wid, int lane) {
#pragma unroll
  for (int q = 0; q < 2; q++) {
    int r = (wid * 2 + q) * 16 + (lane >> 2);
    int cb = ((lane & 3) ^ ((r >> 1) & 3)) * 16;   // swizzled source byte offset
    gload_lds16(tileBase + (long)r * ld + (cb >> 1), lds + (wid * 2 + q) * 512);
  }
}

__device__ __forceinline__ bf16x8 frag_read32(const ushort* lds, int r, int kslot) {
  int off = r * 64 + ((kslot ^ ((r >> 1) & 3)) * 16);
  return *(const bf16x8*)((const char*)lds + off);
}

// ---- inline top-2 over 16 expert probs ----
__device__ __forceinline__ void top2(const float* __restrict__ p, int& i0, int& i1,
                                     float& p0, float& p1) {
  float v0 = -1e30f, v1 = -1e30f; i0 = 0; i1 = 0;
#pragma unroll
  for (int e = 0; e < 16; e++) {
    float v = p[e];
    if (v > v0) { v1 = v0; i1 = i0; v0 = v; i0 = e; }
    else if (v > v1) { v1 = v; i1 = e; }
  }
  float s = 1.0f / (v0 + v1 + 1e-8f);
  p0 = v0 * s; p1 = v1 * s;
}

// -------- f32 -> bf16: hidden + Wout + selected experts (sel inline) --------
__global__ void cvt_all(const float* __restrict__ hidden, const float* __restrict__ wout,
                        const float* __restrict__ eprobs,
                        const float* __restrict__ Wg, const float* __restrict__ Wu,
                        const float* __restrict__ Wd,
                        ushort* __restrict__ h_bf, ushort* __restrict__ wo_bf,
                        ushort* __restrict__ wg_bf, ushort* __restrict__ wu_bf,
                        ushort* __restrict__ wd_bf) {
  __shared__ unsigned smask;
  if (threadIdx.x == 0) {
    unsigned m = 0;
    for (int b = 0; b < 8; b++) {
      int i0, i1; float q0, q1;
      top2(eprobs + b * 16, i0, i1, q0, q1);
      m |= (1u << i0) | (1u << i1);
    }
    smask = m;
  }
  __syncthreads();
  const unsigned selm = smask;

  const long h4 = 2097152L / 4, w4 = 16384000L / 4;
  const long e4 = 1048576L / 4;            // float4s per expert matrix
  const long n4 = h4 + w4 + 48 * e4;
  long stride = (long)gridDim.x * blockDim.x;
  for (long g = (long)blockIdx.x * blockDim.x + threadIdx.x; g < n4; g += stride) {
    const float* src; ushort* dst; long o;
    if (g < h4) { src = hidden; dst = h_bf; o = g; }
    else if (g < h4 + w4) { src = wout; dst = wo_bf; o = g - h4; }
    else {
      long idx = g - h4 - w4;
      int m = (int)(idx / (16 * e4));
      long rem = idx - (long)m * 16 * e4;
      int e = (int)(rem / e4);
      if (!((selm >> e) & 1u)) continue;
      src = (m == 0 ? Wg : (m == 1 ? Wu : Wd));
      dst = (m == 0 ? wg_bf : (m == 1 ? wu_bf : wd_bf));
      o = rem;
    }
    float4 v = ((const float4*)src)[o];
    ((ushort4*)dst)[o] = make_ushort4(f2bf(v.x), f2bf(v.y), f2bf(v.z), f2bf(v.w));
  }
}

// -------- fused gate/up, BM=256 x BN=128, dual-B, 8 waves, counted vmcnt --------
__global__ __launch_bounds__(512, 2) void gateup256(
    const ushort* __restrict__ Hb, const ushort* __restrict__ Wg,
    const ushort* __restrict__ Wu, const float* __restrict__ eprobs,
    ushort* __restrict__ G) {
  constexpr int Hd = 512, I = 2048, S = 512, NT = Hd / 64;
  __shared__ ushort As[2][256 * 64], B1s[2][128 * 64], B2s[2][128 * 64];  // 128 KiB

  int wg = blockIdx.x;
  int swz = (wg & 7) * 64 + (wg >> 3);
  int p = swz >> 5;
  int r5 = swz & 31;
  int rowT = r5 & 1, colT = r5 >> 1;
  const int b = p >> 1;
  int i0, i1; float q0, q1;
  top2(eprobs + b * 16, i0, i1, q0, q1);
  const int eid = (p & 1) ? i1 : i0;
  const int row0 = rowT * 256, col0 = colT * 128;
  const ushort* Ab  = Hb + (long)b * S * Hd + (long)row0 * Hd;
  const ushort* B1b = Wg + (long)eid * I * Hd + (long)col0 * Hd;
  const ushort* B2b = Wu + (long)eid * I * Hd + (long)col0 * Hd;

  const int tid = threadIdx.x, wid = tid >> 6, lane = tid & 63;
  const int wr = wid >> 2, wc = wid & 3;   // wave tile: 128 rows x 32 cols

  f32x4 acc1[8][2] = {};
  f32x4 acc2[8][2] = {};

  auto stage_gu = [&](int kt, int buf) {
    stageT<8, 4>(Ab + kt * 64, Hd, As[buf], wid, lane);
    stageT<8, 2>(B1b + kt * 64, Hd, B1s[buf], wid, lane);
    stageT<8, 2>(B2b + kt * 64, Hd, B2s[buf], wid, lane);
  };

  stage_gu(0, 0);  // 8 vm ops

  for (int kt = 0; kt < NT; kt++) {
    if (kt + 1 < NT) stage_gu(kt + 1, (kt + 1) & 1);  // 8 vm ops
    if (kt + 1 < NT) asm volatile("s_waitcnt vmcnt(8)" ::: "memory");
    else             asm volatile("s_waitcnt vmcnt(0)" ::: "memory");
    __builtin_amdgcn_s_barrier();
    __builtin_amdgcn_sched_barrier(0);
    const ushort* as = As[kt & 1];
    const ushort* b1 = B1s[kt & 1];
    const ushort* b2 = B2s[kt & 1];
#pragma unroll
    for (int ks = 0; ks < 2; ks++) {
      const int kb = ks * 64 + ((lane >> 4) * 16);
      bf16x8 av[8], b1v[2], b2v[2];
#pragma unroll
      for (int i = 0; i < 8; i++) av[i] = frag_read(as, wr * 128 + i * 16 + (lane & 15), kb);
#pragma unroll
      for (int j = 0; j < 2; j++) b1v[j] = frag_read(b1, wc * 32 + j * 16 + (lane & 15), kb);
      __builtin_amdgcn_s_setprio(1);
#pragma unroll
      for (int i = 0; i < 8; i++)
#pragma unroll
        for (int j = 0; j < 2; j++) acc1[i][j] = MFMA16(av[i], b1v[j], acc1[i][j]);
      __builtin_amdgcn_s_setprio(0);
#pragma unroll
      for (int j = 0; j < 2; j++) b2v[j] = frag_read(b2, wc * 32 + j * 16 + (lane & 15), kb);
      __builtin_amdgcn_s_setprio(1);
#pragma unroll
      for (int i = 0; i < 8; i++)
#pragma unroll
        for (int j = 0; j < 2; j++) acc2[i][j] = MFMA16(av[i], b2v[j], acc2[i][j]);
      __builtin_amdgcn_s_setprio(0);
    }
    asm volatile("s_waitcnt lgkmcnt(0)" ::: "memory");
    __builtin_amdgcn_sched_barrier(0);
    __builtin_amdgcn_s_barrier();
  }

  ushort* Gout = G + (long)p * S * I;
#pragma unroll
  for (int i = 0; i < 8; i++) {
    int r = row0 + wr * 128 + i * 16 + ((lane >> 4) * 4);
#pragma unroll
    for (int j = 0; j < 2; j++) {
      int c = col0 + wc * 32 + j * 16 + (lane & 15);
#pragma unroll
      for (int q = 0; q < 4; q++) {
        float g = acc1[i][j][q], u = acc2[i][j][q];
        float sg = g / (1.0f + __expf(-g));
        Gout[(long)(r + q) * I + c] = f2bf(sg * u);
      }
    }
  }
}

// ---------------- fused down GEMM + weighted combine -> bf16 Cb ----------------
__global__ __launch_bounds__(256) void down_fused(
    const ushort* __restrict__ G, const ushort* __restrict__ Wd,
    const float* __restrict__ eprobs, ushort* __restrict__ Cb) {
  constexpr int I = 2048, Hd = 512, S = 512, NT = 64;
  const int b = blockIdx.z;
  const int row0 = blockIdx.x * 128, col0 = blockIdx.y * 64;
  __shared__ ushort As[2][128 * 64], Bs[2][64 * 64];  // 48 KiB
  const int tid = threadIdx.x, wid = tid >> 6, lane = tid & 63;
  const int wr = wid >> 1, wc = wid & 1;   // wave 64 x 32
  int e0, e1; float p0, p1;
  top2(eprobs + b * 16, e0, e1, p0, p1);
  const ushort* A0 = G + ((long)(2 * b) * S + row0) * I;
  const ushort* A1 = G + ((long)(2 * b + 1) * S + row0) * I;
  const ushort* B0 = Wd + ((long)e0 * Hd + col0) * I;
  const ushort* B1 = Wd + ((long)e1 * Hd + col0) * I;

  f32x4 acc[4][2] = {};

  auto stageD = [&](int t2, int buf) {
    const ushort* An = (t2 < 32 ? A0 + t2 * 64 : A1 + (t2 - 32) * 64);
    const ushort* Bn = (t2 < 32 ? B0 + t2 * 64 : B1 + (t2 - 32) * 64);
    stageT<4, 4>(An, I, As[buf], wid, lane);
    stageT<4, 2>(Bn, I, Bs[buf], wid, lane);
  };

  stageD(0, 0);  // 6 vm ops

  for (int t = 0; t < NT; t++) {
    if (t + 1 < NT) stageD(t + 1, (t + 1) & 1);  // 6 vm ops
    if (t + 1 < NT) asm volatile("s_waitcnt vmcnt(6)" ::: "memory");
    else            asm volatile("s_waitcnt vmcnt(0)" ::: "memory");
    __builtin_amdgcn_s_barrier();
    __builtin_amdgcn_sched_barrier(0);
    if (t == 32) {
      float ratio = p0 / p1;
#pragma unroll
      for (int i = 0; i < 4; i++)
#pragma unroll
        for (int j = 0; j < 2; j++) acc[i][j] *= ratio;
    }
#pragma unroll
    for (int ks = 0; ks < 2; ks++) {
      const int kb = ks * 64 + ((lane >> 4) * 16);
      bf16x8 av[4], bv[2];
#pragma unroll
      for (int i = 0; i < 4; i++) av[i] = frag_read(As[t & 1], wr * 64 + i * 16 + (lane & 15), kb);
#pragma unroll
      for (int j = 0; j < 2; j++) bv[j] = frag_read(Bs[t & 1], wc * 32 + j * 16 + (lane & 15), kb);
      __builtin_amdgcn_s_setprio(1);
#pragma unroll
      for (int i = 0; i < 4; i++)
#pragma unroll
        for (int j = 0; j < 2; j++) acc[i][j] = MFMA16(av[i], bv[j], acc[i][j]);
      __builtin_amdgcn_s_setprio(0);
    }
    asm volatile("s_waitcnt lgkmcnt(0)" ::: "memory");
    __builtin_amdgcn_sched_barrier(0);
    __builtin_amdgcn_s_barrier();
  }

  ushort* Co = Cb + ((long)b * S + row0) * Hd + col0;
#pragma unroll
  for (int i = 0; i < 4; i++) {
    int r = wr * 64 + i * 16 + ((lane >> 4) * 4);
#pragma unroll
    for (int j = 0; j < 2; j++) {
      int c = wc * 32 + j * 16 + (lane & 15);
#pragma unroll
      for (int q = 0; q < 4; q++)
        Co[(long)(r + q) * Hd + c] = f2bf(p1 * acc[i][j][q]);
    }
  }
}

// -------- final projection: 128x128, BK=32, 4 waves, 32 KiB LDS -> 4 blocks/CU --------
__global__ __launch_bounds__(256, 4) void gemm128_final(
    const ushort* __restrict__ A,   // [4096][512] bf16 (combined)
    const ushort* __restrict__ B,   // [32000][512] bf16 (Wout)
    float* __restrict__ Out) {      // [4096][32000] f32
  constexpr int K = 512, NTT = 16, LDC = 32000;
  __shared__ ushort As[2][128 * 32], Bs[2][128 * 32];  // 32 KiB

  int wg = blockIdx.x;                          // 8000 blocks, 8000 % 8 == 0
  int swz = (wg & 7) * 1000 + (wg >> 3);
  const int colT = swz / 32, rowT = swz % 32;   // 32 row-tiles share each B col-panel
  const int row0 = rowT * 128, col0 = colT * 128;

  const int tid = threadIdx.x, wid = tid >> 6, lane = tid & 63;
  const int wr = wid >> 1, wc = wid & 1;        // wave tile: 64 rows x 64 cols
  const int l15 = lane & 15;
  const int kslot = lane >> 4;

  const ushort* Ab = A + (long)row0 * K;
  const ushort* Bb = B + (long)col0 * K;
  f32x4 acc[4][4] = {};

  stage32(Ab, K, As[0], wid, lane);
  stage32(Bb, K, Bs[0], wid, lane);

  for (int t = 0; t < NTT; t++) {
    if (t + 1 < NTT) {
      stage32(Ab + (t + 1) * 32, K, As[(t + 1) & 1], wid, lane);
      stage32(Bb + (t + 1) * 32, K, Bs[(t + 1) & 1], wid, lane);
      asm volatile("s_waitcnt vmcnt(4)" ::: "memory");
    } else {
      asm volatile("s_waitcnt vmcnt(0)" ::: "memory");
    }
    __builtin_amdgcn_s_barrier();
    __builtin_amdgcn_sched_barrier(0);
    const ushort* as = As[t & 1];
    const ushort* bs = Bs[t & 1];
    bf16x8 av[4], bv[4];
#pragma unroll
    for (int i = 0; i < 4; i++) av[i] = frag_read32(as, wr * 64 + i * 16 + l15, kslot);
#pragma unroll
    for (int j = 0; j < 4; j++) bv[j] = frag_read32(bs, wc * 64 + j * 16 + l15, kslot);
    __builtin_amdgcn_s_setprio(1);
#pragma unroll
    for (int i = 0; i < 4; i++)
#pragma unroll
      for (int j = 0; j < 4; j++)
        acc[i][j] = MFMA16(av[i], bv[j], acc[i][j]);
    __builtin_amdgcn_s_setprio(0);
    asm volatile("s_waitcnt lgkmcnt(0)" ::: "memory");
    __builtin_amdgcn_sched_barrier(0);
    __builtin_amdgcn_s_barrier();
  }

#pragma unroll
  for (int i = 0; i < 4; i++) {
    int r = row0 + wr * 64 + i * 16 + ((lane >> 4) * 4);
#pragma unroll
    for (int j = 0; j < 4; j++) {
      int c = col0 + wc * 64 + j * 16 + l15;
#pragma unroll
      for (int q = 0; q < 4; q++)
        Out[(long)(r + q) * LDC + c] = acc[i][j][q];
    }
  }
}

extern "C" void kernel_launch(void* const* d_in, const int* in_sizes, int n_in,
                              void* d_out, int out_size, void* d_ws, size_t ws_size,
                              hipStream_t stream) {
  const float* hidden = (const float*)d_in[0];   // [8,512,512]
  const float* eprobs = (const float*)d_in[1];   // [8,16]
  const float* Wg     = (const float*)d_in[2];   // [16,2048,512]
  const float* Wu     = (const float*)d_in[3];   // [16,2048,512]
  const float* Wd     = (const float*)d_in[4];   // [16,512,2048]
  const float* Wout   = (const float*)d_in[5];   // [32000,512]
  float* out = (float*)d_out;                    // [8,512,32000] f32

  char* ws = (char*)d_ws;
  ushort* h_bf  = (ushort*)(ws + 256);         // 8*512*512
  ushort* wg_bf = h_bf  + 2097152L;            // 16*2048*512
  ushort* wu_bf = wg_bf + 16777216L;
  ushort* wd_bf = wu_bf + 16777216L;
  ushort* wo_bf = wd_bf + 16777216L;           // 32000*512
  ushort* Gbuf  = wo_bf + 16384000L;           // 16*512*2048 bf16
  ushort* Cb    = Gbuf  + 16777216L;           // 8*512*512 bf16

  hipLaunchKernelGGL(cvt_all, dim3(4096), dim3(256), 0, stream,
                     hidden, Wout, eprobs, Wg, Wu, Wd, h_bf, wo_bf, wg_bf, wu_bf, wd_bf);
  hipLaunchKernelGGL(gateup256, dim3(512), dim3(512), 0, stream,
                     h_bf, wg_bf, wu_bf, eprobs, Gbuf);
  hipLaunchKernelGGL(down_fused, dim3(4, 8, 8), dim3(256), 0, stream,
                     Gbuf, wd_bf, eprobs, Cb);
  // output projection: 128x128 tiles BK=32, 8000 blocks x 256 thr, 4 blocks/CU
  hipLaunchKernelGGL(gemm128_final, dim3(8000), dim3(256), 0, stream, Cb, wo_bf, out);
}

// Round 10
// 397.766 us; speedup vs baseline: 1.8341x; 1.1420x over previous
//
#include <hip/hip_runtime.h>
#include <hip/hip_bf16.h>
#include <cstdint>

typedef __attribute__((ext_vector_type(8))) short bf16x8;
typedef __attribute__((ext_vector_type(4))) float f32x4;

#define MFMA16(a, b, c) __builtin_amdgcn_mfma_f32_16x16x32_bf16((a), (b), (c), 0, 0, 0)

__device__ __forceinline__ ushort f2bf(float x) {
  union { float f; uint32_t u; } c; c.f = x;
  uint32_t r = (c.u + 0x7FFFu + ((c.u >> 16) & 1u)) >> 16;
  return (ushort)r;
}

__device__ __forceinline__ void gload_lds16(const ushort* g, ushort* l) {
  __builtin_amdgcn_global_load_lds((__attribute__((address_space(1))) void*)g,
                                   (__attribute__((address_space(3))) void*)l, 16, 0, 0);
}

// ---- BK=64 staging (128B rows), swizzle ((r&7)<<4): free 2-way on read ----
template <int NW, int INSTR>
__device__ __forceinline__ void stageT(const ushort* __restrict__ tileBase, int ld,
                                       ushort* lds, int wid, int lane) {
#pragma unroll
  for (int q = 0; q < INSTR; q++) {
    int r = (wid * INSTR + q) * 8 + (lane >> 3);
    int cb = ((lane & 7) * 16) ^ ((r & 7) << 4);
    gload_lds16(tileBase + (long)r * ld + (cb >> 1), lds + (wid * INSTR + q) * 512);
  }
}

__device__ __forceinline__ bf16x8 frag_read(const ushort* lds, int r, int kb) {
  int off = r * 128 + (kb ^ ((r & 7) << 4));
  return *(const bf16x8*)((const char*)lds + off);
}

// ---- BK=32 staging (64B rows). Swizzle: 16B-slot ^= (r>>1)&3. ----
__device__ __forceinline__ void stage32(const ushort* __restrict__ tileBase, int ld,
                                        ushort* lds, int wid, int lane) {
#pragma unroll
  for (int q = 0; q < 2; q++) {
    int r = (wid * 2 + q) * 16 + (lane >> 2);
    int cb = ((lane & 3) ^ ((r >> 1) & 3)) * 16;   // swizzled source byte offset
    gload_lds16(tileBase + (long)r * ld + (cb >> 1), lds + (wid * 2 + q) * 512);
  }
}

__device__ __forceinline__ bf16x8 frag_read32(const ushort* lds, int r, int kslot) {
  int off = r * 64 + ((kslot ^ ((r >> 1) & 3)) * 16);
  return *(const bf16x8*)((const char*)lds + off);
}

// ---- inline top-2 over 16 expert probs ----
__device__ __forceinline__ void top2(const float* __restrict__ p, int& i0, int& i1,
                                     float& p0, float& p1) {
  float v0 = -1e30f, v1 = -1e30f; i0 = 0; i1 = 0;
#pragma unroll
  for (int e = 0; e < 16; e++) {
    float v = p[e];
    if (v > v0) { v1 = v0; i1 = i0; v0 = v; i0 = e; }
    else if (v > v1) { v1 = v; i1 = e; }
  }
  float s = 1.0f / (v0 + v1 + 1e-8f);
  p0 = v0 * s; p1 = v1 * s;
}

// -------- f32 -> bf16: hidden + Wout + selected experts (sel inline) --------
__global__ void cvt_all(const float* __restrict__ hidden, const float* __restrict__ wout,
                        const float* __restrict__ eprobs,
                        const float* __restrict__ Wg, const float* __restrict__ Wu,
                        const float* __restrict__ Wd,
                        ushort* __restrict__ h_bf, ushort* __restrict__ wo_bf,
                        ushort* __restrict__ wg_bf, ushort* __restrict__ wu_bf,
                        ushort* __restrict__ wd_bf) {
  __shared__ unsigned smask;
  if (threadIdx.x == 0) {
    unsigned m = 0;
    for (int b = 0; b < 8; b++) {
      int i0, i1; float q0, q1;
      top2(eprobs + b * 16, i0, i1, q0, q1);
      m |= (1u << i0) | (1u << i1);
    }
    smask = m;
  }
  __syncthreads();
  const unsigned selm = smask;

  const long h4 = 2097152L / 4, w4 = 16384000L / 4;
  const long e4 = 1048576L / 4;            // float4s per expert matrix
  const long n4 = h4 + w4 + 48 * e4;
  long stride = (long)gridDim.x * blockDim.x;
  for (long g = (long)blockIdx.x * blockDim.x + threadIdx.x; g < n4; g += stride) {
    const float* src; ushort* dst; long o;
    if (g < h4) { src = hidden; dst = h_bf; o = g; }
    else if (g < h4 + w4) { src = wout; dst = wo_bf; o = g - h4; }
    else {
      long idx = g - h4 - w4;
      int m = (int)(idx / (16 * e4));
      long rem = idx - (long)m * 16 * e4;
      int e = (int)(rem / e4);
      if (!((selm >> e) & 1u)) continue;
      src = (m == 0 ? Wg : (m == 1 ? Wu : Wd));
      dst = (m == 0 ? wg_bf : (m == 1 ? wu_bf : wd_bf));
      o = rem;
    }
    float4 v = ((const float4*)src)[o];
    ((ushort4*)dst)[o] = make_ushort4(f2bf(v.x), f2bf(v.y), f2bf(v.z), f2bf(v.w));
  }
}

// -------- fused gate/up, BM=256 x BN=128, dual-B, 8 waves, counted vmcnt --------
__global__ __launch_bounds__(512, 2) void gateup256(
    const ushort* __restrict__ Hb, const ushort* __restrict__ Wg,
    const ushort* __restrict__ Wu, const float* __restrict__ eprobs,
    ushort* __restrict__ G) {
  constexpr int Hd = 512, I = 2048, S = 512, NT = Hd / 64;
  __shared__ ushort As[2][256 * 64], B1s[2][128 * 64], B2s[2][128 * 64];  // 128 KiB

  int wg = blockIdx.x;
  int swz = (wg & 7) * 64 + (wg >> 3);
  int p = swz >> 5;
  int r5 = swz & 31;
  int rowT = r5 & 1, colT = r5 >> 1;
  const int b = p >> 1;
  int i0, i1; float q0, q1;
  top2(eprobs + b * 16, i0, i1, q0, q1);
  const int eid = (p & 1) ? i1 : i0;
  const int row0 = rowT * 256, col0 = colT * 128;
  const ushort* Ab  = Hb + (long)b * S * Hd + (long)row0 * Hd;
  const ushort* B1b = Wg + (long)eid * I * Hd + (long)col0 * Hd;
  const ushort* B2b = Wu + (long)eid * I * Hd + (long)col0 * Hd;

  const int tid = threadIdx.x, wid = tid >> 6, lane = tid & 63;
  const int wr = wid >> 2, wc = wid & 3;   // wave tile: 128 rows x 32 cols

  f32x4 acc1[8][2] = {};
  f32x4 acc2[8][2] = {};

  auto stage_gu = [&](int kt, int buf) {
    stageT<8, 4>(Ab + kt * 64, Hd, As[buf], wid, lane);
    stageT<8, 2>(B1b + kt * 64, Hd, B1s[buf], wid, lane);
    stageT<8, 2>(B2b + kt * 64, Hd, B2s[buf], wid, lane);
  };

  stage_gu(0, 0);  // 8 vm ops

  for (int kt = 0; kt < NT; kt++) {
    if (kt + 1 < NT) stage_gu(kt + 1, (kt + 1) & 1);  // 8 vm ops
    if (kt + 1 < NT) asm volatile("s_waitcnt vmcnt(8)" ::: "memory");
    else             asm volatile("s_waitcnt vmcnt(0)" ::: "memory");
    __builtin_amdgcn_s_barrier();
    __builtin_amdgcn_sched_barrier(0);
    const ushort* as = As[kt & 1];
    const ushort* b1 = B1s[kt & 1];
    const ushort* b2 = B2s[kt & 1];
#pragma unroll
    for (int ks = 0; ks < 2; ks++) {
      const int kb = ks * 64 + ((lane >> 4) * 16);
      bf16x8 av[8], b1v[2], b2v[2];
#pragma unroll
      for (int i = 0; i < 8; i++) av[i] = frag_read(as, wr * 128 + i * 16 + (lane & 15), kb);
#pragma unroll
      for (int j = 0; j < 2; j++) b1v[j] = frag_read(b1, wc * 32 + j * 16 + (lane & 15), kb);
      __builtin_amdgcn_s_setprio(1);
#pragma unroll
      for (int i = 0; i < 8; i++)
#pragma unroll
        for (int j = 0; j < 2; j++) acc1[i][j] = MFMA16(av[i], b1v[j], acc1[i][j]);
      __builtin_amdgcn_s_setprio(0);
#pragma unroll
      for (int j = 0; j < 2; j++) b2v[j] = frag_read(b2, wc * 32 + j * 16 + (lane & 15), kb);
      __builtin_amdgcn_s_setprio(1);
#pragma unroll
      for (int i = 0; i < 8; i++)
#pragma unroll
        for (int j = 0; j < 2; j++) acc2[i][j] = MFMA16(av[i], b2v[j], acc2[i][j]);
      __builtin_amdgcn_s_setprio(0);
    }
    asm volatile("s_waitcnt lgkmcnt(0)" ::: "memory");
    __builtin_amdgcn_sched_barrier(0);
    __builtin_amdgcn_s_barrier();
  }

  ushort* Gout = G + (long)p * S * I;
#pragma unroll
  for (int i = 0; i < 8; i++) {
    int r = row0 + wr * 128 + i * 16 + ((lane >> 4) * 4);
#pragma unroll
    for (int j = 0; j < 2; j++) {
      int c = col0 + wc * 32 + j * 16 + (lane & 15);
#pragma unroll
      for (int q = 0; q < 4; q++) {
        float g = acc1[i][j][q], u = acc2[i][j][q];
        float sg = g / (1.0f + __expf(-g));
        Gout[(long)(r + q) * I + c] = f2bf(sg * u);
      }
    }
  }
}

// ---------------- fused down GEMM + weighted combine -> bf16 Cb ----------------
__global__ __launch_bounds__(256) void down_fused(
    const ushort* __restrict__ G, const ushort* __restrict__ Wd,
    const float* __restrict__ eprobs, ushort* __restrict__ Cb) {
  constexpr int I = 2048, Hd = 512, S = 512, NT = 64;
  const int b = blockIdx.z;
  const int row0 = blockIdx.x * 128, col0 = blockIdx.y * 64;
  __shared__ ushort As[2][128 * 64], Bs[2][64 * 64];  // 48 KiB
  const int tid = threadIdx.x, wid = tid >> 6, lane = tid & 63;
  const int wr = wid >> 1, wc = wid & 1;   // wave 64 x 32
  int e0, e1; float p0, p1;
  top2(eprobs + b * 16, e0, e1, p0, p1);
  const ushort* A0 = G + ((long)(2 * b) * S + row0) * I;
  const ushort* A1 = G + ((long)(2 * b + 1) * S + row0) * I;
  const ushort* B0 = Wd + ((long)e0 * Hd + col0) * I;
  const ushort* B1 = Wd + ((long)e1 * Hd + col0) * I;

  f32x4 acc[4][2] = {};

  auto stageD = [&](int t2, int buf) {
    const ushort* An = (t2 < 32 ? A0 + t2 * 64 : A1 + (t2 - 32) * 64);
    const ushort* Bn = (t2 < 32 ? B0 + t2 * 64 : B1 + (t2 - 32) * 64);
    stageT<4, 4>(An, I, As[buf], wid, lane);
    stageT<4, 2>(Bn, I, Bs[buf], wid, lane);
  };

  stageD(0, 0);  // 6 vm ops

  for (int t = 0; t < NT; t++) {
    if (t + 1 < NT) stageD(t + 1, (t + 1) & 1);  // 6 vm ops
    if (t + 1 < NT) asm volatile("s_waitcnt vmcnt(6)" ::: "memory");
    else            asm volatile("s_waitcnt vmcnt(0)" ::: "memory");
    __builtin_amdgcn_s_barrier();
    __builtin_amdgcn_sched_barrier(0);
    if (t == 32) {
      float ratio = p0 / p1;
#pragma unroll
      for (int i = 0; i < 4; i++)
#pragma unroll
        for (int j = 0; j < 2; j++) acc[i][j] *= ratio;
    }
#pragma unroll
    for (int ks = 0; ks < 2; ks++) {
      const int kb = ks * 64 + ((lane >> 4) * 16);
      bf16x8 av[4], bv[2];
#pragma unroll
      for (int i = 0; i < 4; i++) av[i] = frag_read(As[t & 1], wr * 64 + i * 16 + (lane & 15), kb);
#pragma unroll
      for (int j = 0; j < 2; j++) bv[j] = frag_read(Bs[t & 1], wc * 32 + j * 16 + (lane & 15), kb);
      __builtin_amdgcn_s_setprio(1);
#pragma unroll
      for (int i = 0; i < 4; i++)
#pragma unroll
        for (int j = 0; j < 2; j++) acc[i][j] = MFMA16(av[i], bv[j], acc[i][j]);
      __builtin_amdgcn_s_setprio(0);
    }
    asm volatile("s_waitcnt lgkmcnt(0)" ::: "memory");
    __builtin_amdgcn_sched_barrier(0);
    __builtin_amdgcn_s_barrier();
  }

  ushort* Co = Cb + ((long)b * S + row0) * Hd + col0;
#pragma unroll
  for (int i = 0; i < 4; i++) {
    int r = wr * 64 + i * 16 + ((lane >> 4) * 4);
#pragma unroll
    for (int j = 0; j < 2; j++) {
      int c = wc * 32 + j * 16 + (lane & 15);
#pragma unroll
      for (int q = 0; q < 4; q++)
        Co[(long)(r + q) * Hd + c] = f2bf(p1 * acc[i][j][q]);
    }
  }
}

// -------- final projection: 128x128, BK=32, 4 waves, 4 blocks/CU, NT stores --------
__global__ __launch_bounds__(256, 4) void gemm128_final(
    const ushort* __restrict__ A,   // [4096][512] bf16 (combined)
    const ushort* __restrict__ B,   // [32000][512] bf16 (Wout)
    float* __restrict__ Out) {      // [4096][32000] f32
  constexpr int K = 512, NTT = 16, LDC = 32000;
  __shared__ ushort As[2][128 * 32], Bs[2][128 * 32];  // 32 KiB

  int wg = blockIdx.x;                          // 8000 blocks, 8000 % 8 == 0
  int swz = (wg & 7) * 1000 + (wg >> 3);
  const int colT = swz / 32, rowT = swz % 32;   // 32 row-tiles share each B col-panel
  const int row0 = rowT * 128, col0 = colT * 128;

  const int tid = threadIdx.x, wid = tid >> 6, lane = tid & 63;
  const int wr = wid >> 1, wc = wid & 1;        // wave tile: 64 rows x 64 cols
  const int l15 = lane & 15;
  const int kslot = lane >> 4;

  const ushort* Ab = A + (long)row0 * K;
  const ushort* Bb = B + (long)col0 * K;
  f32x4 acc[4][4] = {};

  stage32(Ab, K, As[0], wid, lane);
  stage32(Bb, K, Bs[0], wid, lane);

  for (int t = 0; t < NTT; t++) {
    if (t + 1 < NTT) {
      stage32(Ab + (t + 1) * 32, K, As[(t + 1) & 1], wid, lane);
      stage32(Bb + (t + 1) * 32, K, Bs[(t + 1) & 1], wid, lane);
      asm volatile("s_waitcnt vmcnt(4)" ::: "memory");
    } else {
      asm volatile("s_waitcnt vmcnt(0)" ::: "memory");
    }
    __builtin_amdgcn_s_barrier();
    __builtin_amdgcn_sched_barrier(0);
    const ushort* as = As[t & 1];
    const ushort* bs = Bs[t & 1];
    bf16x8 av[4], bv[4];
#pragma unroll
    for (int i = 0; i < 4; i++) av[i] = frag_read32(as, wr * 64 + i * 16 + l15, kslot);
#pragma unroll
    for (int j = 0; j < 4; j++) bv[j] = frag_read32(bs, wc * 64 + j * 16 + l15, kslot);
    __builtin_amdgcn_s_setprio(1);
#pragma unroll
    for (int i = 0; i < 4; i++)
#pragma unroll
      for (int j = 0; j < 4; j++)
        acc[i][j] = MFMA16(av[i], bv[j], acc[i][j]);
    __builtin_amdgcn_s_setprio(0);
    asm volatile("s_waitcnt lgkmcnt(0)" ::: "memory");
    __builtin_amdgcn_sched_barrier(0);
    __builtin_amdgcn_s_barrier();
  }

  // nt stores: 64B contiguous sectors (16 lanes x dword), no L2 allocation so the
  // write stream stops evicting the A/B panels (FETCH 404 MB -> ~ideal).
#pragma unroll
  for (int i = 0; i < 4; i++) {
    int r = row0 + wr * 64 + i * 16 + ((lane >> 4) * 4);
#pragma unroll
    for (int j = 0; j < 4; j++) {
      int c = col0 + wc * 64 + j * 16 + l15;
#pragma unroll
      for (int q = 0; q < 4; q++)
        __builtin_nontemporal_store(acc[i][j][q], &Out[(long)(r + q) * LDC + c]);
    }
  }
}

extern "C" void kernel_launch(void* const* d_in, const int* in_sizes, int n_in,
                              void* d_out, int out_size, void* d_ws, size_t ws_size,
                              hipStream_t stream) {
  const float* hidden = (const float*)d_in[0];   // [8,512,512]
  const float* eprobs = (const float*)d_in[1];   // [8,16]
  const float* Wg     = (const float*)d_in[2];   // [16,2048,512]
  const float* Wu     = (const float*)d_in[3];   // [16,2048,512]
  const float* Wd     = (const float*)d_in[4];   // [16,512,2048]
  const float* Wout   = (const float*)d_in[5];   // [32000,512]
  float* out = (float*)d_out;                    // [8,512,32000] f32

  char* ws = (char*)d_ws;
  ushort* h_bf  = (ushort*)(ws + 256);         // 8*512*512
  ushort* wg_bf = h_bf  + 2097152L;            // 16*2048*512
  ushort* wu_bf = wg_bf + 16777216L;
  ushort* wd_bf = wu_bf + 16777216L;
  ushort* wo_bf = wd_bf + 16777216L;           // 32000*512
  ushort* Gbuf  = wo_bf + 16384000L;           // 16*512*2048 bf16
  ushort* Cb    = Gbuf  + 16777216L;           // 8*512*512 bf16

  hipLaunchKernelGGL(cvt_all, dim3(4096), dim3(256), 0, stream,
                     hidden, Wout, eprobs, Wg, Wu, Wd, h_bf, wo_bf, wg_bf, wu_bf, wd_bf);
  hipLaunchKernelGGL(gateup256, dim3(512), dim3(512), 0, stream,
                     h_bf, wg_bf, wu_bf, eprobs, Gbuf);
  hipLaunchKernelGGL(down_fused, dim3(4, 8, 8), dim3(256), 0, stream,
                     Gbuf, wd_bf, eprobs, Cb);
  // output projection: 128x128 tiles BK=32, 8000 blocks x 256 thr, 4 blocks/CU, nt stores
  hipLaunchKernelGGL(gemm128_final, dim3(8000), dim3(256), 0, stream, Cb, wo_bf, out);
}